// Round 1
// 1500.018 us; speedup vs baseline: 1.1387x; 1.1387x over previous
//
#include <hip/hip_runtime.h>
#include <hip/hip_bf16.h>

// ---------------------------------------------------------------------------
// SpikeAttention: out = ms(q) @ Mt^T where the linear attention collapses to
//   Mt[j][(h,d)] = SCALE * sum_e kv[h,d,e] * Wp[j, h*64+e]
//   kv[h,d,e]    = sum_n k[n,h,d] * v[n,h,e]
//   q,k,v        = ms_act(xs @ W{q,k,v}^T), xs = ms_act(x)
//
// Precision strategy unchanged from the previous kernel (3-way bf16 split for
// Wq, 2-way for Mt); accumulation order per output element is identical, so
// numerics are bit-identical to the verified 1708us version.
//
// This round: both heavy GEMMs ported from the m97-style 128^2 2-phase
// structure (~800 TF, MfmaUtil 35%) to the 256^2 8-phase counted-vmcnt
// template (T2 swizzle + T3/T4 8-phase counted vmcnt + T5 setprio):
//  - 512 threads, 8 waves as 2x4; per-wave 128x64 output (acc[8][4] f32x4)
//  - LDS = ring of 4 K-half slots (256 rows x 32 cols bf16 = 16KB) per
//    operand = 128 KiB; one half-tile (2 x global_load_lds dwordx4 /thread)
//    staged per phase; vmcnt(6) ONLY at tile boundaries (3 halves in flight)
//  - granule XOR swizzle g ^= (r>>1)&3 applied on BOTH the pre-swizzled
//    global source and the ds_read address -> ds_read_b128 is 2-way (free)
// Slot-ring hazard proof: phase order (ks0,m0)(ks0,m1)(ks1,m0)(ks1,m1);
// B-half h LDS-dead after phase 2h+1, A-half after 2h+2; stage of B-(h+4)
// issues at phase 2h+2, A-(h+4) at 2h+3 (one phase after slot death, behind
// a barrier); boundary vmcnt(6) leaves exactly the newest 3 half-stages in
// flight and proves both halves of the next tile resident.
// ---------------------------------------------------------------------------

#define N_ROWS 65536
#define DIM    1024

using bf16x8 = __attribute__((ext_vector_type(8))) __bf16;
using f32x4  = __attribute__((ext_vector_type(4))) float;

__device__ __forceinline__ float ms_act(float u) {
    float t = fminf(fmaxf(4.0f * u, 0.0f), 4.0f);
    return floorf(t + 0.5f) * 0.25f;
}

__device__ __forceinline__ void gload_lds16(const void* g, void* l) {
    __builtin_amdgcn_global_load_lds(
        (__attribute__((address_space(1))) void*)g,
        (__attribute__((address_space(3))) void*)l, 16, 0, 0);
}

// --- weights fp32 -> bf16 planes --------------------------------------------
// Wb rows: [0..1023]=Wq_hi [1024..2047]=Wk [2048..3071]=Wv
//          [3072..4095]=Wq_mid [4096..5119]=Wq_lo
__global__ __launch_bounds__(256) void k0_convert_w(
    const float* __restrict__ Wq, const float* __restrict__ Wk,
    const float* __restrict__ Wv, __hip_bfloat16* __restrict__ Wb)
{
    const size_t M = (size_t)1024 * 1024;
    int b = blockIdx.x;                 // 3072 blocks, 1024 per matrix
    int mat = b >> 10;
    const float* src = (mat == 0) ? Wq : ((mat == 1) ? Wk : Wv);
    size_t off = (size_t)(b & 1023) * 1024 + (size_t)threadIdx.x * 4;
    float4 u = *(const float4*)(src + off);
    const float* up = (const float*)&u;
    if (mat == 0) {
        union { __hip_bfloat16 h4[4]; uint2 u2; } hi, mid, lo;
#pragma unroll
        for (int i = 0; i < 4; ++i) {
            __hip_bfloat16 h = __float2bfloat16(up[i]);
            float r1 = up[i] - __bfloat162float(h);          // exact (Sterbenz)
            __hip_bfloat16 m = __float2bfloat16(r1);
            float r2 = r1 - __bfloat162float(m);
            hi.h4[i] = h; mid.h4[i] = m; lo.h4[i] = __float2bfloat16(r2);
        }
        *(uint2*)(Wb + 0 * M + off) = hi.u2;
        *(uint2*)(Wb + 3 * M + off) = mid.u2;
        *(uint2*)(Wb + 4 * M + off) = lo.u2;
    } else {
        union { __hip_bfloat16 h4[4]; uint2 u2; } o;
#pragma unroll
        for (int i = 0; i < 4; ++i) o.h4[i] = __float2bfloat16(up[i]);
        *(uint2*)(Wb + (size_t)mat * M + off) = o.u2;
    }
}

// --- xs = ms_act(x), fp32 -> bf16 -------------------------------------------
__global__ __launch_bounds__(256) void k0_quant_x(
    const float* __restrict__ x, __hip_bfloat16* __restrict__ xs)
{
    size_t i = ((size_t)blockIdx.x * 256 + threadIdx.x) * 4;
    float4 u = *(const float4*)(x + i);
    union { __hip_bfloat16 h4[4]; uint2 u2; } o;
    o.h4[0] = __float2bfloat16(ms_act(u.x)); o.h4[1] = __float2bfloat16(ms_act(u.y));
    o.h4[2] = __float2bfloat16(ms_act(u.z)); o.h4[3] = __float2bfloat16(ms_act(u.w));
    *(uint2*)(xs + i) = o.u2;
}

// --- 256x256 8-phase counted-vmcnt GEMM with multi-pass B (split-precision) -
// A[rows][1024] bf16, Bt[rows'][1024] bf16; logical C column block = cb*256.
// Pass p>0 re-runs the K stream with B rows at off1/off2 + (col0&1023),
// accumulating into the same acc. ACT=true: np applies to q blocks (cb<4);
// stores ms_act(C) bf16. ACT=false: np applies to all; stores C fp32.
template <bool ACT>
__global__ __launch_bounds__(512, 2) void gemm256(
    const __hip_bfloat16* __restrict__ A,
    const __hip_bfloat16* __restrict__ Bt,
    __hip_bfloat16* __restrict__ bout,
    float* __restrict__ fout,
    int npass, int off1, int off2)
{
    // A slots: 4 x 16KB at lds + s*16384 ; B slots: 4 x 16KB at +65536
    __shared__ __align__(1024) char lds[131072];

    const int tid  = threadIdx.x;
    const int lane = tid & 63;
    const int wave = tid >> 6;
    const int lm = lane & 15, kg = lane >> 4;
    const int wm = wave >> 2, wn = wave & 3;      // 2 x 4 wave grid

    const int cb = blockIdx.x, rb = blockIdx.y;
    const int row0 = rb * 256, col0 = cb * 256;
    const int np = ACT ? ((cb < 4) ? npass : 1) : npass;
    const int CMAX = np * 64;                     // total half-stages

    // ds_read side: swizzled granule position = kg ^ ((row>>1)&3); row bases
    // are multiples of 16 so only lm contributes.
    const int gsw   = (kg ^ ((lm >> 1) & 3)) * 16;
    const int aBase = (wm * 128 + lm) * 64 + gsw; // byte offset within A slot
    const int bBase = (wn * 64 + lm) * 64 + gsw;  // byte offset within B slot

    // stage side: thread owns linear LDS granules I0, I1 of each 16KB half;
    // the logical granule stored at (r, gpos) is g = gpos ^ ((r>>1)&3), so we
    // pre-swizzle the global source (rule #21: linear dest + inv-swz source).
    const int I0 = tid, I1 = 512 + tid;
    const int r0g = I0 >> 2, r1g = I1 >> 2;
    const int g0 = (I0 & 3) ^ ((r0g >> 1) & 3);
    const int g1 = (I1 & 3) ^ ((r1g >> 1) & 3);
    const size_t aoff0 = (size_t)r0g * DIM + g0 * 8;
    const size_t aoff1 = (size_t)r1g * DIM + g1 * 8;
    const int ldso0 = I0 * 16, ldso1 = I1 * 16;
    const __hip_bfloat16* Arow = A + (size_t)row0 * DIM;

    f32x4 acc[8][4] = {};

    // stage half-stage cc: B-half h at cc=2h, A-half h at cc=2h+1; slot=h&3.
    auto stage = [&](int cc) {
        const int h = cc >> 1, slot = h & 3, tile = h >> 1;
        const int k0 = ((tile & 15) << 6) + ((h & 1) << 5);
        if (cc & 1) {          // A half
            char* d = lds + slot * 16384;
            gload_lds16(Arow + aoff0 + k0, d + ldso0);
            gload_lds16(Arow + aoff1 + k0, d + ldso1);
        } else {               // B half
            const int pass = tile >> 4;
            const int cbase = (pass == 0) ? col0
                            : ((pass == 1) ? off1 + (col0 & 1023)
                                           : off2 + (col0 & 1023));
            const __hip_bfloat16* Brow = Bt + (size_t)cbase * DIM;
            char* d = lds + 65536 + slot * 16384;
            gload_lds16(Brow + aoff0 + k0, d + ldso0);
            gload_lds16(Brow + aoff1 + k0, d + ldso1);
        }
    };

    int c = 0;
    // Prologue: 7 half-stages (tile0 = c0..3 + 3 in flight), then vmcnt(6)
    // proves tile0 resident with exactly 3 half-stages (6 loads) outstanding.
#pragma unroll
    for (int i = 0; i < 7; ++i) { stage(c); ++c; }
    asm volatile("s_waitcnt vmcnt(6)" ::: "memory");
    __builtin_amdgcn_s_barrier();

    bf16x8 af[4], bfr[4];

#define LD_B(S) do {                                                         \
    const char* bp_ = lds + 65536 + (S) * 16384 + bBase;                     \
    bfr[0] = *(const bf16x8*)(bp_);                                          \
    bfr[1] = *(const bf16x8*)(bp_ + 1024);                                   \
    bfr[2] = *(const bf16x8*)(bp_ + 2048);                                   \
    bfr[3] = *(const bf16x8*)(bp_ + 3072);                                   \
} while (0)

#define LD_A(S, MH) do {                                                     \
    const char* ap_ = lds + (S) * 16384 + aBase + (MH) * 4096;               \
    af[0] = *(const bf16x8*)(ap_);                                           \
    af[1] = *(const bf16x8*)(ap_ + 1024);                                    \
    af[2] = *(const bf16x8*)(ap_ + 2048);                                    \
    af[3] = *(const bf16x8*)(ap_ + 3072);                                    \
} while (0)

#define PHASE(S, MH, BND) do {                                               \
    if ((MH) == 0) LD_B(S);                                                  \
    LD_A(S, MH);                                                             \
    if (c < CMAX) stage(c);                                                  \
    ++c;                                                                     \
    __builtin_amdgcn_s_barrier();                                            \
    asm volatile("s_waitcnt lgkmcnt(0)" ::: "memory");                       \
    __builtin_amdgcn_sched_barrier(0);                                       \
    __builtin_amdgcn_s_setprio(1);                                           \
    _Pragma("unroll")                                                        \
    for (int i2_ = 0; i2_ < 4; ++i2_) {                                      \
        _Pragma("unroll")                                                    \
        for (int j_ = 0; j_ < 4; ++j_)                                       \
            acc[(MH) * 4 + i2_][j_] = __builtin_amdgcn_mfma_f32_16x16x32_bf16( \
                af[i2_], bfr[j_], acc[(MH) * 4 + i2_][j_], 0, 0, 0);         \
    }                                                                        \
    __builtin_amdgcn_s_setprio(0);                                           \
    __builtin_amdgcn_sched_barrier(0);                                       \
    if (BND) asm volatile("s_waitcnt vmcnt(6)" ::: "memory");                \
    __builtin_amdgcn_s_barrier();                                            \
} while (0)

    // 2 K-tiles (static slots 0,1 then 2,3) per iteration = 8 phases.
    for (int it = 0; it < np * 8; ++it) {
        PHASE(0, 0, false); PHASE(0, 1, false);
        PHASE(1, 0, false); PHASE(1, 1, true);
        PHASE(2, 0, false); PHASE(2, 1, false);
        PHASE(3, 0, false); PHASE(3, 1, true);
    }

#undef PHASE
#undef LD_A
#undef LD_B

    // C/D layout (m89-verified): col = lane&15, row = (lane>>4)*4 + reg
    const int r0 = row0 + wm * 128;
    if (ACT) {
        const int mi = cb >> 2;  // 0:q 1:k 2:v
        __hip_bfloat16* dst = bout + (size_t)mi * ((size_t)N_ROWS * DIM);
        const int c0 = (col0 & 1023) + wn * 64;
#pragma unroll
        for (int i = 0; i < 8; ++i)
#pragma unroll
            for (int j = 0; j < 4; ++j)
#pragma unroll
                for (int r = 0; r < 4; ++r) {
                    int row = r0 + i * 16 + kg * 4 + r;
                    int col = c0 + j * 16 + lm;
                    dst[(size_t)row * DIM + col] = __float2bfloat16(ms_act(acc[i][j][r]));
                }
    } else {
        const int c0 = col0 + wn * 64;
#pragma unroll
        for (int i = 0; i < 8; ++i)
#pragma unroll
            for (int j = 0; j < 4; ++j)
#pragma unroll
                for (int r = 0; r < 4; ++r) {
                    int row = r0 + i * 16 + kg * 4 + r;
                    int col = c0 + j * 16 + lm;
                    fout[(size_t)row * DIM + col] = acc[i][j][r];
                }
    }
}

// --- kv[h,d,e] = sum_n k[n,h*64+d] * v[n,h*64+e]  (exact fp32 atomics) -------
__global__ __launch_bounds__(256) void k3_kv(
    const __hip_bfloat16* __restrict__ kb, const __hip_bfloat16* __restrict__ vb,
    float* __restrict__ kv)
{
    const int h = blockIdx.y;       // 0..15
    const int chunk = blockIdx.x;   // 0..63, each block reduces 1024 rows
    const int tid = threadIdx.x;
    __shared__ float lk[64][64];
    __shared__ float lv[64][64];
    float acc[4][4] = {};
    const int d0 = (tid & 15) * 4, e0 = (tid >> 4) * 4;
    const int r = tid >> 3, c8 = (tid & 7) * 8;

    for (int s = 0; s < 16; ++s) {
        const size_t n0 = (size_t)chunk * 1024 + (size_t)s * 64;
        __syncthreads();
#pragma unroll
        for (int p = 0; p < 2; ++p) {
            int row = p * 32 + r;
            uint4 kd = *(const uint4*)(kb + (n0 + row) * DIM + h * 64 + c8);
            uint4 vd = *(const uint4*)(vb + (n0 + row) * DIM + h * 64 + c8);
            float* dk = &lk[row][c8];
            float* dv = &lv[row][c8];
            dk[0] = __uint_as_float(kd.x << 16); dk[1] = __uint_as_float(kd.x & 0xffff0000u);
            dk[2] = __uint_as_float(kd.y << 16); dk[3] = __uint_as_float(kd.y & 0xffff0000u);
            dk[4] = __uint_as_float(kd.z << 16); dk[5] = __uint_as_float(kd.z & 0xffff0000u);
            dk[6] = __uint_as_float(kd.w << 16); dk[7] = __uint_as_float(kd.w & 0xffff0000u);
            dv[0] = __uint_as_float(vd.x << 16); dv[1] = __uint_as_float(vd.x & 0xffff0000u);
            dv[2] = __uint_as_float(vd.y << 16); dv[3] = __uint_as_float(vd.y & 0xffff0000u);
            dv[4] = __uint_as_float(vd.z << 16); dv[5] = __uint_as_float(vd.z & 0xffff0000u);
            dv[6] = __uint_as_float(vd.w << 16); dv[7] = __uint_as_float(vd.w & 0xffff0000u);
        }
        __syncthreads();
#pragma unroll 4
        for (int n = 0; n < 64; ++n) {
            float4 kk = *(const float4*)&lk[n][d0];
            float4 vv = *(const float4*)&lv[n][e0];
            const float* kp = (const float*)&kk;
#pragma unroll
            for (int i = 0; i < 4; ++i) {
                acc[i][0] = fmaf(kp[i], vv.x, acc[i][0]);
                acc[i][1] = fmaf(kp[i], vv.y, acc[i][1]);
                acc[i][2] = fmaf(kp[i], vv.z, acc[i][2]);
                acc[i][3] = fmaf(kp[i], vv.w, acc[i][3]);
            }
        }
    }
#pragma unroll
    for (int i = 0; i < 4; ++i)
#pragma unroll
        for (int j = 0; j < 4; ++j)
            atomicAdd(&kv[(h * 64 + d0 + i) * 64 + e0 + j], acc[i][j]);
}

// --- Mt[j][c=(h,d)] = 0.25 * sum_e kv[h,d,e] * Wp[j, h*64+e] ----------------
// Emits a 2-way bf16 split: rows [0..1023]=hi, [1024..2047]=lo.
__global__ __launch_bounds__(256) void k4_build_M(
    const float* __restrict__ kv, const float* __restrict__ Wp,
    __hip_bfloat16* __restrict__ Mt)
{
    const int j = blockIdx.x;
    const int c0 = threadIdx.x * 4;
    const int hh = c0 >> 6;
    const int d0 = c0 & 63;
    float s[4] = {0, 0, 0, 0};
    const float* kvh = kv + (size_t)hh * 64 * 64;
    const float* wp  = Wp + (size_t)j * DIM + hh * 64;
    for (int e = 0; e < 64; e += 4) {
        float4 w = *(const float4*)(wp + e);
#pragma unroll
        for (int i = 0; i < 4; ++i) {
            float4 a = *(const float4*)(kvh + (d0 + i) * 64 + e);
            s[i] += a.x * w.x + a.y * w.y + a.z * w.z + a.w * w.w;
        }
    }
    union { __hip_bfloat16 h4[4]; uint2 u2; } hi, lo;
#pragma unroll
    for (int i = 0; i < 4; ++i) {
        float m = 0.25f * s[i];
        __hip_bfloat16 h = __float2bfloat16(m);
        hi.h4[i] = h;
        lo.h4[i] = __float2bfloat16(m - __bfloat162float(h));
    }
    *(uint2*)(Mt + (size_t)j * DIM + c0) = hi.u2;
    *(uint2*)(Mt + (size_t)(1024 + j) * DIM + c0) = lo.u2;
}

extern "C" void kernel_launch(void* const* d_in, const int* in_sizes, int n_in,
                              void* d_out, int out_size, void* d_ws, size_t ws_size,
                              hipStream_t stream) {
    const float* x  = (const float*)d_in[0];
    const float* Wq = (const float*)d_in[1];
    const float* Wk = (const float*)d_in[2];
    const float* Wv = (const float*)d_in[3];
    const float* Wp = (const float*)d_in[4];
    float* out = (float*)d_out;

    char* ws = (char*)d_ws;
    const size_t MB = 1024ull * 1024;
    __hip_bfloat16* xs  = (__hip_bfloat16*)(ws);             // 128 MB
    __hip_bfloat16* qkv = (__hip_bfloat16*)(ws + 128 * MB);  // 3 x 128 MB (q,k,v)
    __hip_bfloat16* Wb  = (__hip_bfloat16*)(ws + 512 * MB);  // 5 x 2 MB planes
    __hip_bfloat16* Mt  = (__hip_bfloat16*)(ws + 522 * MB);  // 2 x 2 MB (hi,lo)
    float*          kv  = (float*)(ws + 526 * MB);           // 256 KB

    k0_convert_w<<<3072, 256, 0, stream>>>(Wq, Wk, Wv, Wb);
    k0_quant_x<<<65536, 256, 0, stream>>>(x, xs);
    hipMemsetAsync(kv, 0, 16 * 64 * 64 * sizeof(float), stream);

    // fused QKV GEMM + ms_act epilogue; q columns accumulate 3 split planes
    gemm256<true><<<dim3(12, 256), 512, 0, stream>>>(
        xs, Wb, qkv, nullptr, 3, 3072, 4096);

    // kv = k^T v per head (exact in fp32)
    k3_kv<<<dim3(64, 16), 256, 0, stream>>>(
        qkv + 1ull * N_ROWS * DIM, qkv + 2ull * N_ROWS * DIM, kv);

    // Mt = SCALE * blockdiag(kv) @ Wp^T, split hi/lo
    k4_build_M<<<1024, 256, 0, stream>>>(kv, Wp, Mt);

    // out = q @ (Mt_hi + Mt_lo)^T, fp32 out
    gemm256<false><<<dim3(4, 256), 512, 0, stream>>>(
        qkv, Mt, nullptr, out, 2, 1024, 0);
}

// Round 4
// 1478.480 us; speedup vs baseline: 1.1553x; 1.0146x over previous
//
#include <hip/hip_runtime.h>
#include <hip/hip_bf16.h>

// ---------------------------------------------------------------------------
// SpikeAttention: out = ms(q) @ Mt^T where the linear attention collapses to
//   Mt[j][(h,d)] = SCALE * sum_e kv[h,d,e] * Wp[j, h*64+e]
//   kv[h,d,e]    = sum_n k[n,h,d] * v[n,h,e]
//   q,k,v        = ms_act(xs @ W{q,k,v}^T), xs = ms_act(x)
//
// Round 4 = BISECT. The Round-2/3 kernel (32x32x16 MFMA + XCD swizzle +
// static stage decode) killed the container twice; Round-1 ran clean. This
// round is the Round-1 kernel VERBATIM plus ONLY the T1 bijective chunked
// XCD swizzle (pure index remap, hand-verified bijective for nwg=3072/1024).
// If this passes, the 32x32 rewrite is implicated; if it fails, the swizzle
// (or infra) is.
//
// Template (from Round 1, measured 727us QKV, 0 bank conflicts):
//  - 512 threads, 8 waves as 2x4; per-wave 128x64 output (acc[8][4] f32x4)
//  - 16x16x32 bf16 MFMA; LDS ring of 4 K-half slots per operand (128 KiB)
//  - 8-phase counted-vmcnt schedule; vmcnt(6) only at tile boundaries
//  - granule XOR swizzle g ^= (r>>1)&3 on both pre-swizzled global source
//    and ds_read address
// ---------------------------------------------------------------------------

#define N_ROWS 65536
#define DIM    1024

using bf16x8 = __attribute__((ext_vector_type(8))) __bf16;
using f32x4  = __attribute__((ext_vector_type(4))) float;

__device__ __forceinline__ float ms_act(float u) {
    float t = fminf(fmaxf(4.0f * u, 0.0f), 4.0f);
    return floorf(t + 0.5f) * 0.25f;
}

__device__ __forceinline__ void gload_lds16(const void* g, void* l) {
    __builtin_amdgcn_global_load_lds(
        (__attribute__((address_space(1))) void*)g,
        (__attribute__((address_space(3))) void*)l, 16, 0, 0);
}

// --- weights fp32 -> bf16 planes --------------------------------------------
// Wb rows: [0..1023]=Wq_hi [1024..2047]=Wk [2048..3071]=Wv
//          [3072..4095]=Wq_mid [4096..5119]=Wq_lo
__global__ __launch_bounds__(256) void k0_convert_w(
    const float* __restrict__ Wq, const float* __restrict__ Wk,
    const float* __restrict__ Wv, __hip_bfloat16* __restrict__ Wb)
{
    const size_t M = (size_t)1024 * 1024;
    int b = blockIdx.x;                 // 3072 blocks, 1024 per matrix
    int mat = b >> 10;
    const float* src = (mat == 0) ? Wq : ((mat == 1) ? Wk : Wv);
    size_t off = (size_t)(b & 1023) * 1024 + (size_t)threadIdx.x * 4;
    float4 u = *(const float4*)(src + off);
    const float* up = (const float*)&u;
    if (mat == 0) {
        union { __hip_bfloat16 h4[4]; uint2 u2; } hi, mid, lo;
#pragma unroll
        for (int i = 0; i < 4; ++i) {
            __hip_bfloat16 h = __float2bfloat16(up[i]);
            float r1 = up[i] - __bfloat162float(h);          // exact (Sterbenz)
            __hip_bfloat16 m = __float2bfloat16(r1);
            float r2 = r1 - __bfloat162float(m);
            hi.h4[i] = h; mid.h4[i] = m; lo.h4[i] = __float2bfloat16(r2);
        }
        *(uint2*)(Wb + 0 * M + off) = hi.u2;
        *(uint2*)(Wb + 3 * M + off) = mid.u2;
        *(uint2*)(Wb + 4 * M + off) = lo.u2;
    } else {
        union { __hip_bfloat16 h4[4]; uint2 u2; } o;
#pragma unroll
        for (int i = 0; i < 4; ++i) o.h4[i] = __float2bfloat16(up[i]);
        *(uint2*)(Wb + (size_t)mat * M + off) = o.u2;
    }
}

// --- xs = ms_act(x), fp32 -> bf16 -------------------------------------------
__global__ __launch_bounds__(256) void k0_quant_x(
    const float* __restrict__ x, __hip_bfloat16* __restrict__ xs)
{
    size_t i = ((size_t)blockIdx.x * 256 + threadIdx.x) * 4;
    float4 u = *(const float4*)(x + i);
    union { __hip_bfloat16 h4[4]; uint2 u2; } o;
    o.h4[0] = __float2bfloat16(ms_act(u.x)); o.h4[1] = __float2bfloat16(ms_act(u.y));
    o.h4[2] = __float2bfloat16(ms_act(u.z)); o.h4[3] = __float2bfloat16(ms_act(u.w));
    *(uint2*)(xs + i) = o.u2;
}

// --- 256x256 8-phase counted-vmcnt GEMM with multi-pass B (split-precision) -
// A[rows][1024] bf16, Bt[rows'][1024] bf16; logical C column block = cb*256.
// Pass p>0 re-runs the K stream with B rows at off1/off2 + (col0&1023),
// accumulating into the same acc. ACT=true: np applies to q blocks (cb<4);
// stores ms_act(C) bf16. ACT=false: np applies to all; stores C fp32.
template <bool ACT>
__global__ __launch_bounds__(512, 2) void gemm256(
    const __hip_bfloat16* __restrict__ A,
    const __hip_bfloat16* __restrict__ Bt,
    __hip_bfloat16* __restrict__ bout,
    float* __restrict__ fout,
    int npass, int off1, int off2)
{
    // A slots: 4 x 16KB at lds + s*16384 ; B slots: 4 x 16KB at +65536
    __shared__ __align__(1024) char lds[131072];

    const int tid  = threadIdx.x;
    const int lane = tid & 63;
    const int wave = tid >> 6;
    const int lm = lane & 15, kg = lane >> 4;
    const int wm = wave >> 2, wn = wave & 3;      // 2 x 4 wave grid

    // T1: bijective chunked XCD swizzle (nwg % 8 == 0 for both launches).
    // Blocks with the same rb land on the same XCD -> A panel is an L2 hit.
    const int nx = gridDim.x;
    const int nwg = nx * gridDim.y;
    const int orig = blockIdx.y * nx + blockIdx.x;
    const int lg = (orig & 7) * (nwg >> 3) + (orig >> 3);
    const int cb = lg % nx, rb = lg / nx;

    const int row0 = rb * 256, col0 = cb * 256;
    const int np = ACT ? ((cb < 4) ? npass : 1) : npass;
    const int CMAX = np * 64;                     // total half-stages

    // ds_read side: swizzled granule position = kg ^ ((row>>1)&3); row bases
    // are multiples of 16 so only lm contributes.
    const int gsw   = (kg ^ ((lm >> 1) & 3)) * 16;
    const int aBase = (wm * 128 + lm) * 64 + gsw; // byte offset within A slot
    const int bBase = (wn * 64 + lm) * 64 + gsw;  // byte offset within B slot

    // stage side: thread owns linear LDS granules I0, I1 of each 16KB half;
    // the logical granule stored at (r, gpos) is g = gpos ^ ((r>>1)&3), so we
    // pre-swizzle the global source (rule #21: linear dest + inv-swz source).
    const int I0 = tid, I1 = 512 + tid;
    const int r0g = I0 >> 2, r1g = I1 >> 2;
    const int g0 = (I0 & 3) ^ ((r0g >> 1) & 3);
    const int g1 = (I1 & 3) ^ ((r1g >> 1) & 3);
    const size_t aoff0 = (size_t)r0g * DIM + g0 * 8;
    const size_t aoff1 = (size_t)r1g * DIM + g1 * 8;
    const int ldso0 = I0 * 16, ldso1 = I1 * 16;
    const __hip_bfloat16* Arow = A + (size_t)row0 * DIM;

    f32x4 acc[8][4] = {};

    // stage half-stage cc: B-half h at cc=2h, A-half h at cc=2h+1; slot=h&3.
    auto stage = [&](int cc) {
        const int h = cc >> 1, slot = h & 3, tile = h >> 1;
        const int k0 = ((tile & 15) << 6) + ((h & 1) << 5);
        if (cc & 1) {          // A half
            char* d = lds + slot * 16384;
            gload_lds16(Arow + aoff0 + k0, d + ldso0);
            gload_lds16(Arow + aoff1 + k0, d + ldso1);
        } else {               // B half
            const int pass = tile >> 4;
            const int cbase = (pass == 0) ? col0
                            : ((pass == 1) ? off1 + (col0 & 1023)
                                           : off2 + (col0 & 1023));
            const __hip_bfloat16* Brow = Bt + (size_t)cbase * DIM;
            char* d = lds + 65536 + slot * 16384;
            gload_lds16(Brow + aoff0 + k0, d + ldso0);
            gload_lds16(Brow + aoff1 + k0, d + ldso1);
        }
    };

    int c = 0;
    // Prologue: 7 half-stages (tile0 = c0..3 + 3 in flight), then vmcnt(6)
    // proves tile0 resident with exactly 3 half-stages (6 loads) outstanding.
#pragma unroll
    for (int i = 0; i < 7; ++i) { stage(c); ++c; }
    asm volatile("s_waitcnt vmcnt(6)" ::: "memory");
    __builtin_amdgcn_s_barrier();

    bf16x8 af[4], bfr[4];

#define LD_B(S) do {                                                         \
    const char* bp_ = lds + 65536 + (S) * 16384 + bBase;                     \
    bfr[0] = *(const bf16x8*)(bp_);                                          \
    bfr[1] = *(const bf16x8*)(bp_ + 1024);                                   \
    bfr[2] = *(const bf16x8*)(bp_ + 2048);                                   \
    bfr[3] = *(const bf16x8*)(bp_ + 3072);                                   \
} while (0)

#define LD_A(S, MH) do {                                                     \
    const char* ap_ = lds + (S) * 16384 + aBase + (MH) * 4096;               \
    af[0] = *(const bf16x8*)(ap_);                                           \
    af[1] = *(const bf16x8*)(ap_ + 1024);                                    \
    af[2] = *(const bf16x8*)(ap_ + 2048);                                    \
    af[3] = *(const bf16x8*)(ap_ + 3072);                                    \
} while (0)

#define PHASE(S, MH, BND) do {                                               \
    if ((MH) == 0) LD_B(S);                                                  \
    LD_A(S, MH);                                                             \
    if (c < CMAX) stage(c);                                                  \
    ++c;                                                                     \
    __builtin_amdgcn_s_barrier();                                            \
    asm volatile("s_waitcnt lgkmcnt(0)" ::: "memory");                       \
    __builtin_amdgcn_sched_barrier(0);                                       \
    __builtin_amdgcn_s_setprio(1);                                           \
    _Pragma("unroll")                                                        \
    for (int i2_ = 0; i2_ < 4; ++i2_) {                                      \
        _Pragma("unroll")                                                    \
        for (int j_ = 0; j_ < 4; ++j_)                                       \
            acc[(MH) * 4 + i2_][j_] = __builtin_amdgcn_mfma_f32_16x16x32_bf16( \
                af[i2_], bfr[j_], acc[(MH) * 4 + i2_][j_], 0, 0, 0);         \
    }                                                                        \
    __builtin_amdgcn_s_setprio(0);                                           \
    __builtin_amdgcn_sched_barrier(0);                                       \
    if (BND) asm volatile("s_waitcnt vmcnt(6)" ::: "memory");                \
    __builtin_amdgcn_s_barrier();                                            \
} while (0)

    // 2 K-tiles (static slots 0,1 then 2,3) per iteration = 8 phases.
    for (int it = 0; it < np * 8; ++it) {
        PHASE(0, 0, false); PHASE(0, 1, false);
        PHASE(1, 0, false); PHASE(1, 1, true);
        PHASE(2, 0, false); PHASE(2, 1, false);
        PHASE(3, 0, false); PHASE(3, 1, true);
    }

#undef PHASE
#undef LD_A
#undef LD_B

    // C/D layout (m89-verified): col = lane&15, row = (lane>>4)*4 + reg
    const int r0 = row0 + wm * 128;
    if (ACT) {
        const int mi = cb >> 2;  // 0:q 1:k 2:v
        __hip_bfloat16* dst = bout + (size_t)mi * ((size_t)N_ROWS * DIM);
        const int c0 = (col0 & 1023) + wn * 64;
#pragma unroll
        for (int i = 0; i < 8; ++i)
#pragma unroll
            for (int j = 0; j < 4; ++j)
#pragma unroll
                for (int r = 0; r < 4; ++r) {
                    int row = r0 + i * 16 + kg * 4 + r;
                    int col = c0 + j * 16 + lm;
                    dst[(size_t)row * DIM + col] = __float2bfloat16(ms_act(acc[i][j][r]));
                }
    } else {
        const int c0 = col0 + wn * 64;
#pragma unroll
        for (int i = 0; i < 8; ++i)
#pragma unroll
            for (int j = 0; j < 4; ++j)
#pragma unroll
                for (int r = 0; r < 4; ++r) {
                    int row = r0 + i * 16 + kg * 4 + r;
                    int col = c0 + j * 16 + lm;
                    fout[(size_t)row * DIM + col] = acc[i][j][r];
                }
    }
}

// --- kv[h,d,e] = sum_n k[n,h*64+d] * v[n,h*64+e]  (exact fp32 atomics) -------
__global__ __launch_bounds__(256) void k3_kv(
    const __hip_bfloat16* __restrict__ kb, const __hip_bfloat16* __restrict__ vb,
    float* __restrict__ kv)
{
    const int h = blockIdx.y;       // 0..15
    const int chunk = blockIdx.x;   // 0..63, each block reduces 1024 rows
    const int tid = threadIdx.x;
    __shared__ float lk[64][64];
    __shared__ float lv[64][64];
    float acc[4][4] = {};
    const int d0 = (tid & 15) * 4, e0 = (tid >> 4) * 4;
    const int r = tid >> 3, c8 = (tid & 7) * 8;

    for (int s = 0; s < 16; ++s) {
        const size_t n0 = (size_t)chunk * 1024 + (size_t)s * 64;
        __syncthreads();
#pragma unroll
        for (int p = 0; p < 2; ++p) {
            int row = p * 32 + r;
            uint4 kd = *(const uint4*)(kb + (n0 + row) * DIM + h * 64 + c8);
            uint4 vd = *(const uint4*)(vb + (n0 + row) * DIM + h * 64 + c8);
            float* dk = &lk[row][c8];
            float* dv = &lv[row][c8];
            dk[0] = __uint_as_float(kd.x << 16); dk[1] = __uint_as_float(kd.x & 0xffff0000u);
            dk[2] = __uint_as_float(kd.y << 16); dk[3] = __uint_as_float(kd.y & 0xffff0000u);
            dk[4] = __uint_as_float(kd.z << 16); dk[5] = __uint_as_float(kd.z & 0xffff0000u);
            dk[6] = __uint_as_float(kd.w << 16); dk[7] = __uint_as_float(kd.w & 0xffff0000u);
            dv[0] = __uint_as_float(vd.x << 16); dv[1] = __uint_as_float(vd.x & 0xffff0000u);
            dv[2] = __uint_as_float(vd.y << 16); dv[3] = __uint_as_float(vd.y & 0xffff0000u);
            dv[4] = __uint_as_float(vd.z << 16); dv[5] = __uint_as_float(vd.z & 0xffff0000u);
            dv[6] = __uint_as_float(vd.w << 16); dv[7] = __uint_as_float(vd.w & 0xffff0000u);
        }
        __syncthreads();
#pragma unroll 4
        for (int n = 0; n < 64; ++n) {
            float4 kk = *(const float4*)&lk[n][d0];
            float4 vv = *(const float4*)&lv[n][e0];
            const float* kp = (const float*)&kk;
#pragma unroll
            for (int i = 0; i < 4; ++i) {
                acc[i][0] = fmaf(kp[i], vv.x, acc[i][0]);
                acc[i][1] = fmaf(kp[i], vv.y, acc[i][1]);
                acc[i][2] = fmaf(kp[i], vv.z, acc[i][2]);
                acc[i][3] = fmaf(kp[i], vv.w, acc[i][3]);
            }
        }
    }
#pragma unroll
    for (int i = 0; i < 4; ++i)
#pragma unroll
        for (int j = 0; j < 4; ++j)
            atomicAdd(&kv[(h * 64 + d0 + i) * 64 + e0 + j], acc[i][j]);
}

// --- Mt[j][c=(h,d)] = 0.25 * sum_e kv[h,d,e] * Wp[j, h*64+e] ----------------
// Emits a 2-way bf16 split: rows [0..1023]=hi, [1024..2047]=lo.
__global__ __launch_bounds__(256) void k4_build_M(
    const float* __restrict__ kv, const float* __restrict__ Wp,
    __hip_bfloat16* __restrict__ Mt)
{
    const int j = blockIdx.x;
    const int c0 = threadIdx.x * 4;
    const int hh = c0 >> 6;
    const int d0 = c0 & 63;
    float s[4] = {0, 0, 0, 0};
    const float* kvh = kv + (size_t)hh * 64 * 64;
    const float* wp  = Wp + (size_t)j * DIM + hh * 64;
    for (int e = 0; e < 64; e += 4) {
        float4 w = *(const float4*)(wp + e);
#pragma unroll
        for (int i = 0; i < 4; ++i) {
            float4 a = *(const float4*)(kvh + (d0 + i) * 64 + e);
            s[i] += a.x * w.x + a.y * w.y + a.z * w.z + a.w * w.w;
        }
    }
    union { __hip_bfloat16 h4[4]; uint2 u2; } hi, lo;
#pragma unroll
    for (int i = 0; i < 4; ++i) {
        float m = 0.25f * s[i];
        __hip_bfloat16 h = __float2bfloat16(m);
        hi.h4[i] = h;
        lo.h4[i] = __float2bfloat16(m - __bfloat162float(h));
    }
    *(uint2*)(Mt + (size_t)j * DIM + c0) = hi.u2;
    *(uint2*)(Mt + (size_t)(1024 + j) * DIM + c0) = lo.u2;
}

extern "C" void kernel_launch(void* const* d_in, const int* in_sizes, int n_in,
                              void* d_out, int out_size, void* d_ws, size_t ws_size,
                              hipStream_t stream) {
    const float* x  = (const float*)d_in[0];
    const float* Wq = (const float*)d_in[1];
    const float* Wk = (const float*)d_in[2];
    const float* Wv = (const float*)d_in[3];
    const float* Wp = (const float*)d_in[4];
    float* out = (float*)d_out;

    char* ws = (char*)d_ws;
    const size_t MB = 1024ull * 1024;
    __hip_bfloat16* xs  = (__hip_bfloat16*)(ws);             // 128 MB
    __hip_bfloat16* qkv = (__hip_bfloat16*)(ws + 128 * MB);  // 3 x 128 MB (q,k,v)
    __hip_bfloat16* Wb  = (__hip_bfloat16*)(ws + 512 * MB);  // 5 x 2 MB planes
    __hip_bfloat16* Mt  = (__hip_bfloat16*)(ws + 522 * MB);  // 2 x 2 MB (hi,lo)
    float*          kv  = (float*)(ws + 526 * MB);           // 256 KB

    k0_convert_w<<<3072, 256, 0, stream>>>(Wq, Wk, Wv, Wb);
    k0_quant_x<<<65536, 256, 0, stream>>>(x, xs);
    hipMemsetAsync(kv, 0, 16 * 64 * 64 * sizeof(float), stream);

    // fused QKV GEMM + ms_act epilogue; q columns accumulate 3 split planes
    gemm256<true><<<dim3(12, 256), 512, 0, stream>>>(
        xs, Wb, qkv, nullptr, 3, 3072, 4096);

    // kv = k^T v per head (exact in fp32)
    k3_kv<<<dim3(64, 16), 256, 0, stream>>>(
        qkv + 1ull * N_ROWS * DIM, qkv + 2ull * N_ROWS * DIM, kv);

    // Mt = SCALE * blockdiag(kv) @ Wp^T, split hi/lo
    k4_build_M<<<1024, 256, 0, stream>>>(kv, Wp, Mt);

    // out = q @ (Mt_hi + Mt_lo)^T, fp32 out
    gemm256<false><<<dim3(4, 256), 512, 0, stream>>>(
        qkv, Mt, nullptr, out, 2, 1024, 0);
}